// Round 1
// baseline (1068.620 us; speedup 1.0000x reference)
//
#include <hip/hip_runtime.h>

#define N_NODES   50000
#define N_EDGES   800000
#define HID       64
#define NUM_GRAPHS 50
#define EPS       1e-5f

// ---------------------------------------------------------------------------
// Degree count (per dst node) + node count per graph.
__global__ __launch_bounds__(256) void k_count(const int* __restrict__ dst,
                                               const int* __restrict__ batch,
                                               float* __restrict__ cnt,
                                               float* __restrict__ gcnt) {
    int tid = blockIdx.x * blockDim.x + threadIdx.x;
    int stride = gridDim.x * blockDim.x;
    for (int e = tid; e < N_EDGES; e += stride) unsafeAtomicAdd(&cnt[dst[e]], 1.0f);
    for (int n = tid; n < N_NODES; n += stride) unsafeAtomicAdd(&gcnt[batch[n]], 1.0f);
}

// ---------------------------------------------------------------------------
// Edge message: m = relu(concat(xin[src], ea) @ W + b); aggr[dst] += m
// One wave per edge (2 edges/iter for FMA-chain ILP). Lane h owns W column h
// in VGPRs; per-edge inputs are wave-uniform -> scalar loads feed the FMAs.
__global__ __launch_bounds__(256) void k_edge(const float* __restrict__ xin,   // [N,64]
                                              const float* __restrict__ ea,    // [E,32]
                                              const int*   __restrict__ src,
                                              const int*   __restrict__ dst,
                                              const float* __restrict__ W,     // [96,64]
                                              const float* __restrict__ bias,  // [64]
                                              float* __restrict__ aggr) {      // [N,64]
    const int lane = threadIdx.x & 63;
    const int wid  = (blockIdx.x * blockDim.x + threadIdx.x) >> 6;
    const int nw   = (gridDim.x * blockDim.x) >> 6;

    float w[96];
#pragma unroll
    for (int k = 0; k < 96; ++k) w[k] = W[k * 64 + lane];
    const float bb = bias[lane];

    for (int e0 = wid * 2; e0 < N_EDGES; e0 += nw * 2) {
        const int e1 = e0 + 1;  // N_EDGES even, e0 even -> always valid
        const int s0 = __builtin_amdgcn_readfirstlane(src[e0]);
        const int s1 = __builtin_amdgcn_readfirstlane(src[e1]);
        const int d0 = __builtin_amdgcn_readfirstlane(dst[e0]);
        const int d1 = __builtin_amdgcn_readfirstlane(dst[e1]);
        const float* __restrict__ x0 = xin + (size_t)s0 * 64;
        const float* __restrict__ x1 = xin + (size_t)s1 * 64;
        const float* __restrict__ a0 = ea + (size_t)e0 * 32;
        const float* __restrict__ a1 = ea + (size_t)e1 * 32;
        float acc0 = bb, acc1 = bb;
#pragma unroll
        for (int k = 0; k < 64; ++k) { acc0 += x0[k] * w[k]; acc1 += x1[k] * w[k]; }
#pragma unroll
        for (int k = 0; k < 32; ++k) { acc0 += a0[k] * w[64 + k]; acc1 += a1[k] * w[64 + k]; }
        acc0 = fmaxf(acc0, 0.f);
        acc1 = fmaxf(acc1, 0.f);
        unsafeAtomicAdd(&aggr[(size_t)d0 * 64 + lane], acc0);
        unsafeAtomicAdd(&aggr[(size_t)d1 * 64 + lane], acc1);
    }
}

// ---------------------------------------------------------------------------
// h = xin @ Wr + aggr/max(cnt,1); also accumulate BN sum/sumsq per feature.
__global__ __launch_bounds__(256) void k_combine(const float* __restrict__ xin,  // [N,64]
                                                 const float* __restrict__ Wr,   // [64,64]
                                                 const float* __restrict__ aggr, // [N,64]
                                                 const float* __restrict__ cnt,  // [N]
                                                 float* __restrict__ h,          // [N,64]
                                                 float* __restrict__ stats) {    // [128]
    const int lane = threadIdx.x & 63;
    const int wv   = threadIdx.x >> 6;  // wave in block (0..3)
    const int wid  = (blockIdx.x * blockDim.x + threadIdx.x) >> 6;
    const int nw   = (gridDim.x * blockDim.x) >> 6;

    float w[64];
#pragma unroll
    for (int k = 0; k < 64; ++k) w[k] = Wr[k * 64 + lane];

    float rs = 0.f, rq = 0.f;
    for (int n = wid; n < N_NODES; n += nw) {
        const float* __restrict__ xr = xin + (size_t)n * 64;
        const float c = cnt[n];  // uniform
        float acc = aggr[(size_t)n * 64 + lane] / fmaxf(c, 1.0f);
#pragma unroll
        for (int k = 0; k < 64; ++k) acc += xr[k] * w[k];
        h[(size_t)n * 64 + lane] = acc;
        rs += acc;
        rq += acc * acc;
    }
    __shared__ float ssum[4][64];
    __shared__ float ssq[4][64];
    ssum[wv][lane] = rs;
    ssq[wv][lane]  = rq;
    __syncthreads();
    if (threadIdx.x < 64) {
        float s = ssum[0][lane] + ssum[1][lane] + ssum[2][lane] + ssum[3][lane];
        unsafeAtomicAdd(&stats[lane], s);
    } else if (threadIdx.x < 128) {
        int l = threadIdx.x - 64;
        float q = ssq[0][l] + ssq[1][l] + ssq[2][l] + ssq[3][l];
        unsafeAtomicAdd(&stats[64 + l], q);
    }
}

// ---------------------------------------------------------------------------
// Fold BN stats into per-feature scale/shift.
__global__ void k_bnfin(const float* __restrict__ stats, const float* __restrict__ g,
                        const float* __restrict__ be, float* __restrict__ ss) {
    int f = threadIdx.x;
    if (f < 64) {
        float mu  = stats[f] * (1.0f / (float)N_NODES);
        float var = stats[64 + f] * (1.0f / (float)N_NODES) - mu * mu;
        float sc  = g[f] * rsqrtf(var + EPS);
        ss[f]      = sc;
        ss[64 + f] = be[f] - mu * sc;
    }
}

// ---------------------------------------------------------------------------
// hn = relu(h * scale + shift), vectorized float4.
__global__ __launch_bounds__(256) void k_bnapply(const float* __restrict__ h,
                                                 const float* __restrict__ ss,
                                                 float* __restrict__ hn) {
    int tid = blockIdx.x * blockDim.x + threadIdx.x;
    int stride = gridDim.x * blockDim.x;
    const int total = N_NODES * 64 / 4;
    for (int i = tid; i < total; i += stride) {
        float4 v = ((const float4*)h)[i];
        int f = (i & 15) * 4;  // (i*4) % 64
        float4 r;
        r.x = fmaxf(v.x * ss[f + 0] + ss[64 + f + 0], 0.f);
        r.y = fmaxf(v.y * ss[f + 1] + ss[64 + f + 1], 0.f);
        r.z = fmaxf(v.z * ss[f + 2] + ss[64 + f + 2], 0.f);
        r.w = fmaxf(v.w * ss[f + 3] + ss[64 + f + 3], 0.f);
        ((float4*)hn)[i] = r;
    }
}

// ---------------------------------------------------------------------------
// Per-graph sums of hn (mean finished in k_final).
__global__ __launch_bounds__(256) void k_pool(const float* __restrict__ hn,
                                              const int* __restrict__ batch,
                                              float* __restrict__ gsum) {
    const int lane = threadIdx.x & 63;
    const int wid  = (blockIdx.x * blockDim.x + threadIdx.x) >> 6;
    const int nw   = (gridDim.x * blockDim.x) >> 6;
    for (int n = wid; n < N_NODES; n += nw) {
        int g = batch[n];  // uniform per wave
        unsafeAtomicAdd(&gsum[g * 64 + lane], hn[(size_t)n * 64 + lane]);
    }
}

// ---------------------------------------------------------------------------
// out[g] = dot(gsum[g]/max(gcnt,1), Wro) + bro
__global__ void k_final(const float* __restrict__ gsum, const float* __restrict__ gcnt,
                        const float* __restrict__ Wro, const float* __restrict__ bro,
                        float* __restrict__ out) {
    int g = blockIdx.x;
    int lane = threadIdx.x;  // 64 threads
    float v = gsum[g * 64 + lane] / fmaxf(gcnt[g], 1.0f) * Wro[lane];
#pragma unroll
    for (int off = 32; off > 0; off >>= 1) v += __shfl_down(v, off, 64);
    if (lane == 0) out[g] = v + bro[0];
}

// ---------------------------------------------------------------------------
extern "C" void kernel_launch(void* const* d_in, const int* in_sizes, int n_in,
                              void* d_out, int out_size, void* d_ws, size_t ws_size,
                              hipStream_t stream) {
    (void)in_sizes; (void)n_in; (void)out_size; (void)ws_size;
    const float* x    = (const float*)d_in[0];
    const int*   ei   = (const int*)d_in[1];   // [2, E]
    const float* ea   = (const float*)d_in[2];
    const int*   batch= (const int*)d_in[3];
    const float* Wn1  = (const float*)d_in[4];
    const float* bn1  = (const float*)d_in[5];
    const float* Wr1  = (const float*)d_in[6];
    const float* g1   = (const float*)d_in[7];
    const float* be1  = (const float*)d_in[8];
    const float* Wn2  = (const float*)d_in[9];
    const float* bn2  = (const float*)d_in[10];
    const float* Wr2  = (const float*)d_in[11];
    const float* g2   = (const float*)d_in[12];
    const float* be2  = (const float*)d_in[13];
    const float* Wro  = (const float*)d_in[14];
    const float* bro  = (const float*)d_in[15];
    const int* src = ei;
    const int* dst = ei + N_EDGES;

    float* ws = (float*)d_ws;
    float* cnt    = ws;               // 50048 (padded)
    float* gcnt   = cnt + 50048;      // 64
    float* stats1 = gcnt + 64;        // 128
    float* stats2 = stats1 + 128;     // 128
    float* gsum   = stats2 + 128;     // 3200
    float* aggr   = gsum + 3200;      // N*64   <- end of zeroed region
    float* h      = aggr + (size_t)N_NODES * 64;
    float* hn     = h + (size_t)N_NODES * 64;
    float* ss1    = hn + (size_t)N_NODES * 64;  // 128
    float* ss2    = ss1 + 128;                  // 128

    size_t zero_floats = (size_t)(50048 + 64 + 128 + 128 + 3200) + (size_t)N_NODES * 64;
    hipMemsetAsync(d_ws, 0, zero_floats * sizeof(float), stream);

    k_count<<<512, 256, 0, stream>>>(dst, batch, cnt, gcnt);

    // ---- layer 1 ----
    k_edge<<<2048, 256, 0, stream>>>(x, ea, src, dst, Wn1, bn1, aggr);
    k_combine<<<1024, 256, 0, stream>>>(x, Wr1, aggr, cnt, h, stats1);
    k_bnfin<<<1, 64, 0, stream>>>(stats1, g1, be1, ss1);
    k_bnapply<<<2048, 256, 0, stream>>>(h, ss1, hn);

    // ---- layer 2 ----
    hipMemsetAsync(aggr, 0, (size_t)N_NODES * 64 * sizeof(float), stream);
    k_edge<<<2048, 256, 0, stream>>>(hn, ea, src, dst, Wn2, bn2, aggr);
    k_combine<<<1024, 256, 0, stream>>>(hn, Wr2, aggr, cnt, h, stats2);
    k_bnfin<<<1, 64, 0, stream>>>(stats2, g2, be2, ss2);
    k_bnapply<<<2048, 256, 0, stream>>>(h, ss2, hn);

    // ---- readout ----
    k_pool<<<1024, 256, 0, stream>>>(hn, batch, gsum);
    k_final<<<NUM_GRAPHS, 64, 0, stream>>>(gsum, gcnt, Wro, bro, (float*)d_out);
}

// Round 2
// 767.040 us; speedup vs baseline: 1.3932x; 1.3932x over previous
//
#include <hip/hip_runtime.h>

#define N_NODES   50000
#define N_EDGES   800000
#define HID       64
#define NUM_GRAPHS 50
#define EPS       1e-5f
#define NB_COMBINE 256   // blocks for k_combine (partials buffer sized to this)

// ---------------------------------------------------------------------------
// Degree count (per dst node) via random-address atomics (shallow chains).
__global__ __launch_bounds__(256) void k_count(const int* __restrict__ dst,
                                               float* __restrict__ cnt) {
    int tid = blockIdx.x * blockDim.x + threadIdx.x;
    int stride = gridDim.x * blockDim.x;
    for (int e = tid; e < N_EDGES; e += stride) unsafeAtomicAdd(&cnt[dst[e]], 1.0f);
}

// ---------------------------------------------------------------------------
// Per-graph node counts via binary search on the sorted batch array. No atomics.
__global__ void k_gcnt(const int* __restrict__ batch, float* __restrict__ gcnt) {
    int g = threadIdx.x;
    if (g >= NUM_GRAPHS) return;
    auto lb = [&](int val) {
        int lo = 0, hi = N_NODES;
        while (lo < hi) { int mid = (lo + hi) >> 1; if (batch[mid] < val) lo = mid + 1; else hi = mid; }
        return lo;
    };
    gcnt[g] = (float)(lb(g + 1) - lb(g));
}

// ---------------------------------------------------------------------------
// Edge message: m = relu(concat(xin[src], ea) @ W + b); aggr[dst] += m
// One wave per edge (2 edges/iter for FMA-chain ILP). Lane h owns W column h
// in VGPRs; per-edge inputs are wave-uniform -> scalar loads feed the FMAs.
__global__ __launch_bounds__(256) void k_edge(const float* __restrict__ xin,   // [N,64]
                                              const float* __restrict__ ea,    // [E,32]
                                              const int*   __restrict__ src,
                                              const int*   __restrict__ dst,
                                              const float* __restrict__ W,     // [96,64]
                                              const float* __restrict__ bias,  // [64]
                                              float* __restrict__ aggr) {      // [N,64]
    const int lane = threadIdx.x & 63;
    const int wid  = (blockIdx.x * blockDim.x + threadIdx.x) >> 6;
    const int nw   = (gridDim.x * blockDim.x) >> 6;

    float w[96];
#pragma unroll
    for (int k = 0; k < 96; ++k) w[k] = W[k * 64 + lane];
    const float bb = bias[lane];

    for (int e0 = wid * 2; e0 < N_EDGES; e0 += nw * 2) {
        const int e1 = e0 + 1;  // N_EDGES even, e0 even -> always valid
        const int s0 = __builtin_amdgcn_readfirstlane(src[e0]);
        const int s1 = __builtin_amdgcn_readfirstlane(src[e1]);
        const int d0 = __builtin_amdgcn_readfirstlane(dst[e0]);
        const int d1 = __builtin_amdgcn_readfirstlane(dst[e1]);
        const float* __restrict__ x0 = xin + (size_t)s0 * 64;
        const float* __restrict__ x1 = xin + (size_t)s1 * 64;
        const float* __restrict__ a0 = ea + (size_t)e0 * 32;
        const float* __restrict__ a1 = ea + (size_t)e1 * 32;
        float acc0 = bb, acc1 = bb;
#pragma unroll
        for (int k = 0; k < 64; ++k) { acc0 += x0[k] * w[k]; acc1 += x1[k] * w[k]; }
#pragma unroll
        for (int k = 0; k < 32; ++k) { acc0 += a0[k] * w[64 + k]; acc1 += a1[k] * w[64 + k]; }
        acc0 = fmaxf(acc0, 0.f);
        acc1 = fmaxf(acc1, 0.f);
        unsafeAtomicAdd(&aggr[(size_t)d0 * 64 + lane], acc0);
        unsafeAtomicAdd(&aggr[(size_t)d1 * 64 + lane], acc1);
    }
}

// ---------------------------------------------------------------------------
// h = xin @ Wr + aggr/max(cnt,1); per-block BN partial sums (no atomics).
__global__ __launch_bounds__(256) void k_combine(const float* __restrict__ xin,  // [N,64]
                                                 const float* __restrict__ Wr,   // [64,64]
                                                 const float* __restrict__ aggr, // [N,64]
                                                 const float* __restrict__ cnt,  // [N]
                                                 float* __restrict__ h,          // [N,64]
                                                 float* __restrict__ partial) {  // [NB,128]
    const int lane = threadIdx.x & 63;
    const int wv   = threadIdx.x >> 6;  // wave in block (0..3)
    const int wid  = (blockIdx.x * blockDim.x + threadIdx.x) >> 6;
    const int nw   = (gridDim.x * blockDim.x) >> 6;

    float w[64];
#pragma unroll
    for (int k = 0; k < 64; ++k) w[k] = Wr[k * 64 + lane];

    float rs = 0.f, rq = 0.f;
    for (int n = wid; n < N_NODES; n += nw) {
        const float* __restrict__ xr = xin + (size_t)n * 64;
        const float c = cnt[n];  // uniform
        float acc = aggr[(size_t)n * 64 + lane] / fmaxf(c, 1.0f);
#pragma unroll
        for (int k = 0; k < 64; ++k) acc += xr[k] * w[k];
        h[(size_t)n * 64 + lane] = acc;
        rs += acc;
        rq += acc * acc;
    }
    __shared__ float ssum[4][64];
    __shared__ float ssq[4][64];
    ssum[wv][lane] = rs;
    ssq[wv][lane]  = rq;
    __syncthreads();
    if (threadIdx.x < 64) {
        float s = ssum[0][lane] + ssum[1][lane] + ssum[2][lane] + ssum[3][lane];
        partial[blockIdx.x * 128 + lane] = s;
    } else if (threadIdx.x < 128) {
        int l = threadIdx.x - 64;
        float q = ssq[0][l] + ssq[1][l] + ssq[2][l] + ssq[3][l];
        partial[blockIdx.x * 128 + 64 + l] = q;
    }
}

// ---------------------------------------------------------------------------
// Reduce per-block partials -> per-feature scale/shift. 1 block, 128 threads.
__global__ void k_bnfin(const float* __restrict__ partial, const float* __restrict__ g,
                        const float* __restrict__ be, float* __restrict__ ss) {
    __shared__ float tot[128];
    int t = threadIdx.x;
    float s = 0.f;
    for (int b = 0; b < NB_COMBINE; ++b) s += partial[b * 128 + t];
    tot[t] = s;
    __syncthreads();
    if (t < 64) {
        float mu  = tot[t] * (1.0f / (float)N_NODES);
        float var = tot[64 + t] * (1.0f / (float)N_NODES) - mu * mu;
        float sc  = g[t] * rsqrtf(var + EPS);
        ss[t]      = sc;
        ss[64 + t] = be[t] - mu * sc;
    }
}

// ---------------------------------------------------------------------------
// hn = relu(h * scale + shift), vectorized float4.
__global__ __launch_bounds__(256) void k_bnapply(const float* __restrict__ h,
                                                 const float* __restrict__ ss,
                                                 float* __restrict__ hn) {
    int tid = blockIdx.x * blockDim.x + threadIdx.x;
    int stride = gridDim.x * blockDim.x;
    const int total = N_NODES * 64 / 4;
    for (int i = tid; i < total; i += stride) {
        float4 v = ((const float4*)h)[i];
        int f = (i & 15) * 4;  // (i*4) % 64
        float4 r;
        r.x = fmaxf(v.x * ss[f + 0] + ss[64 + f + 0], 0.f);
        r.y = fmaxf(v.y * ss[f + 1] + ss[64 + f + 1], 0.f);
        r.z = fmaxf(v.z * ss[f + 2] + ss[64 + f + 2], 0.f);
        r.w = fmaxf(v.w * ss[f + 3] + ss[64 + f + 3], 0.f);
        ((float4*)hn)[i] = r;
    }
}

// ---------------------------------------------------------------------------
// Per-graph sums of hn. batch is sorted: each wave owns a contiguous node run,
// accumulates in registers, flushes one atomic per graph transition.
__global__ __launch_bounds__(256) void k_pool(const float* __restrict__ hn,
                                              const int* __restrict__ batch,
                                              float* __restrict__ gsum) {
    const int lane = threadIdx.x & 63;
    const int wid  = (blockIdx.x * blockDim.x + threadIdx.x) >> 6;
    const int nw   = (gridDim.x * blockDim.x) >> 6;
    const int chunk = (N_NODES + nw - 1) / nw;
    const int n0 = wid * chunk;
    const int n1 = min(n0 + chunk, N_NODES);
    int curg = -1;
    float acc = 0.f;
    for (int n = n0; n < n1; ++n) {
        int g = __builtin_amdgcn_readfirstlane(batch[n]);
        if (g != curg) {
            if (curg >= 0) unsafeAtomicAdd(&gsum[curg * 64 + lane], acc);
            curg = g;
            acc = 0.f;
        }
        acc += hn[(size_t)n * 64 + lane];
    }
    if (curg >= 0) unsafeAtomicAdd(&gsum[curg * 64 + lane], acc);
}

// ---------------------------------------------------------------------------
// out[g] = dot(gsum[g]/max(gcnt,1), Wro) + bro
__global__ void k_final(const float* __restrict__ gsum, const float* __restrict__ gcnt,
                        const float* __restrict__ Wro, const float* __restrict__ bro,
                        float* __restrict__ out) {
    int g = blockIdx.x;
    int lane = threadIdx.x;  // 64 threads
    float v = gsum[g * 64 + lane] / fmaxf(gcnt[g], 1.0f) * Wro[lane];
#pragma unroll
    for (int off = 32; off > 0; off >>= 1) v += __shfl_down(v, off, 64);
    if (lane == 0) out[g] = v + bro[0];
}

// ---------------------------------------------------------------------------
extern "C" void kernel_launch(void* const* d_in, const int* in_sizes, int n_in,
                              void* d_out, int out_size, void* d_ws, size_t ws_size,
                              hipStream_t stream) {
    (void)in_sizes; (void)n_in; (void)out_size; (void)ws_size;
    const float* x    = (const float*)d_in[0];
    const int*   ei   = (const int*)d_in[1];   // [2, E]
    const float* ea   = (const float*)d_in[2];
    const int*   batch= (const int*)d_in[3];
    const float* Wn1  = (const float*)d_in[4];
    const float* bn1  = (const float*)d_in[5];
    const float* Wr1  = (const float*)d_in[6];
    const float* g1   = (const float*)d_in[7];
    const float* be1  = (const float*)d_in[8];
    const float* Wn2  = (const float*)d_in[9];
    const float* bn2  = (const float*)d_in[10];
    const float* Wr2  = (const float*)d_in[11];
    const float* g2   = (const float*)d_in[12];
    const float* be2  = (const float*)d_in[13];
    const float* Wro  = (const float*)d_in[14];
    const float* bro  = (const float*)d_in[15];
    const int* src = ei;
    const int* dst = ei + N_EDGES;

    float* ws = (float*)d_ws;
    // zeroed region: [cnt | gsum | aggr]
    float* cnt    = ws;                         // 50048 (padded)
    float* gsum   = cnt + 50048;                // 3200
    float* aggr   = gsum + 3200;                // N*64  <- end of zeroed region
    // non-zeroed:
    float* h      = aggr + (size_t)N_NODES * 64;
    float* hn     = h + (size_t)N_NODES * 64;
    float* gcnt   = hn + (size_t)N_NODES * 64;  // 64
    float* part1  = gcnt + 64;                  // NB_COMBINE*128
    float* part2  = part1 + NB_COMBINE * 128;   // NB_COMBINE*128
    float* ss1    = part2 + NB_COMBINE * 128;   // 128
    float* ss2    = ss1 + 128;                  // 128

    size_t zero_floats = (size_t)(50048 + 3200) + (size_t)N_NODES * 64;
    hipMemsetAsync(d_ws, 0, zero_floats * sizeof(float), stream);

    k_count<<<512, 256, 0, stream>>>(dst, cnt);
    k_gcnt<<<1, 64, 0, stream>>>(batch, gcnt);

    // ---- layer 1 ----
    k_edge<<<2048, 256, 0, stream>>>(x, ea, src, dst, Wn1, bn1, aggr);
    k_combine<<<NB_COMBINE, 256, 0, stream>>>(x, Wr1, aggr, cnt, h, part1);
    k_bnfin<<<1, 128, 0, stream>>>(part1, g1, be1, ss1);
    k_bnapply<<<2048, 256, 0, stream>>>(h, ss1, hn);

    // ---- layer 2 ----
    hipMemsetAsync(aggr, 0, (size_t)N_NODES * 64 * sizeof(float), stream);
    k_edge<<<2048, 256, 0, stream>>>(hn, ea, src, dst, Wn2, bn2, aggr);
    k_combine<<<NB_COMBINE, 256, 0, stream>>>(hn, Wr2, aggr, cnt, h, part2);
    k_bnfin<<<1, 128, 0, stream>>>(part2, g2, be2, ss2);
    k_bnapply<<<2048, 256, 0, stream>>>(h, ss2, hn);

    // ---- readout ----
    k_pool<<<256, 256, 0, stream>>>(hn, batch, gsum);
    k_final<<<NUM_GRAPHS, 64, 0, stream>>>(gsum, gcnt, Wro, bro, (float*)d_out);
}

// Round 3
// 580.996 us; speedup vs baseline: 1.8393x; 1.3202x over previous
//
#include <hip/hip_runtime.h>

#define N_NODES   50000
#define N_EDGES   800000
#define HID       64
#define NUM_GRAPHS 50
#define EPS       1e-5f
#define NB_COMBINE 256   // blocks for k_combine (partials buffer sized to this)

typedef __attribute__((ext_vector_type(8))) short short8;
typedef __attribute__((ext_vector_type(4))) float f32x4;

__device__ __forceinline__ unsigned short bfbits(float x) {
    __bf16 h = (__bf16)x;
    return __builtin_bit_cast(unsigned short, h);
}
__device__ __forceinline__ float bffloat(unsigned short b) {
    return __builtin_bit_cast(float, (unsigned int)b << 16);
}

// ---------------------------------------------------------------------------
// Degree count (per dst node) via random-address atomics (shallow chains).
__global__ __launch_bounds__(256) void k_count(const int* __restrict__ dst,
                                               float* __restrict__ cnt) {
    int tid = blockIdx.x * blockDim.x + threadIdx.x;
    int stride = gridDim.x * blockDim.x;
    for (int e = tid; e < N_EDGES; e += stride) unsafeAtomicAdd(&cnt[dst[e]], 1.0f);
}

// ---------------------------------------------------------------------------
// Per-graph node counts via binary search on the sorted batch array. No atomics.
__global__ void k_gcnt(const int* __restrict__ batch, float* __restrict__ gcnt) {
    int g = threadIdx.x;
    if (g >= NUM_GRAPHS) return;
    auto lb = [&](int val) {
        int lo = 0, hi = N_NODES;
        while (lo < hi) { int mid = (lo + hi) >> 1; if (batch[mid] < val) lo = mid + 1; else hi = mid; }
        return lo;
    };
    gcnt[g] = (float)(lb(g + 1) - lb(g));
}

// ---------------------------------------------------------------------------
// Weight prep: W[96][64] fp32 -> Wt hi/lo [64][104] bf16 (transposed, padded).
__global__ void k_prepW(const float* __restrict__ W, unsigned short* __restrict__ Whi,
                        unsigned short* __restrict__ Wlo) {
    int t = blockIdx.x * blockDim.x + threadIdx.x;
    if (t >= 96 * 64) return;
    int k = t >> 6, n = t & 63;
    float x = W[t];
    unsigned short hb = bfbits(x);
    float lof = x - bffloat(hb);
    Whi[n * 104 + k] = hb;
    Wlo[n * 104 + k] = bfbits(lof);
}

// ---------------------------------------------------------------------------
// Edge message via MFMA (bf16 hi/lo split, 3-product fp32-accurate GEMM):
// per WG: 64 edges; A = concat(x[src], ea) [64,96] staged hi/lo in LDS;
// B = Wt fragments resident in registers; C tile per wave = 32x32 quadrant.
// Epilogue: +bias, ReLU, coalesced row atomics onto aggr[dst].
__global__ __launch_bounds__(256) void k_edge(const float* __restrict__ xin,   // [N,64]
                                              const float* __restrict__ ea,    // [E,32]
                                              const int*   __restrict__ src,
                                              const int*   __restrict__ dst,
                                              const unsigned short* __restrict__ Whi, // [64][104]
                                              const unsigned short* __restrict__ Wlo,
                                              const float* __restrict__ bias,  // [64]
                                              float* __restrict__ aggr) {      // [N,64]
    __shared__ __align__(16) unsigned short Ahi[64 * 104];
    __shared__ __align__(16) unsigned short Alo[64 * 104];
    __shared__ int lsrc[64];
    __shared__ int ldst[64];

    const int tid  = threadIdx.x;
    const int lane = tid & 63;
    const int w    = tid >> 6;        // wave 0..3
    const int e0   = blockIdx.x * 64;

    const int fr    = lane & 15;      // M-row / N-col within 16x16 tile
    const int koff  = (lane >> 4) * 8;
    const int nbase = (w & 1) * 32;   // wave's N quadrant
    const int mbase = (w >> 1) * 32;  // wave's M quadrant

    // B fragments resident: 2 N-tiles x 3 K-blocks x {hi,lo}
    short8 bh[2][3], bl[2][3];
#pragma unroll
    for (int n = 0; n < 2; ++n)
#pragma unroll
        for (int kb = 0; kb < 3; ++kb) {
            const int row = nbase + n * 16 + fr;
            bh[n][kb] = *(const short8*)(Whi + row * 104 + kb * 32 + koff);
            bl[n][kb] = *(const short8*)(Wlo + row * 104 + kb * 32 + koff);
        }

    if (tid < 64) { lsrc[tid] = src[e0 + tid]; ldst[tid] = dst[e0 + tid]; }
    __syncthreads();

    // gather x rows -> cols [0,64): 2 rows per wave-iter (float2 per lane)
    {
        const int jj = lane & 31;
        const int half = lane >> 5;
#pragma unroll
        for (int it = 0; it < 8; ++it) {
            const int r = w * 16 + it * 2 + half;
            const int s = lsrc[r];
            float2 v = *((const float2*)(xin + (size_t)s * 64) + jj);
            unsigned short h0 = bfbits(v.x), h1 = bfbits(v.y);
            unsigned short l0 = bfbits(v.x - bffloat(h0));
            unsigned short l1 = bfbits(v.y - bffloat(h1));
            ((unsigned int*)Ahi)[r * 52 + jj] = ((unsigned int)h1 << 16) | h0;
            ((unsigned int*)Alo)[r * 52 + jj] = ((unsigned int)l1 << 16) | l0;
        }
    }
    // gather ea -> cols [64,96)
#pragma unroll
    for (int it = 0; it < 4; ++it) {
        const int f = tid + it * 256;
        const int e = f >> 4, q = f & 15;
        float2 v = *((const float2*)(ea + (size_t)(e0 + e) * 32) + q);
        unsigned short h0 = bfbits(v.x), h1 = bfbits(v.y);
        unsigned short l0 = bfbits(v.x - bffloat(h0));
        unsigned short l1 = bfbits(v.y - bffloat(h1));
        ((unsigned int*)Ahi)[e * 52 + 32 + q] = ((unsigned int)h1 << 16) | h0;
        ((unsigned int*)Alo)[e * 52 + 32 + q] = ((unsigned int)l1 << 16) | l0;
    }
    __syncthreads();

    f32x4 acc[2][2] = {};
#pragma unroll
    for (int kb = 0; kb < 3; ++kb) {
        short8 ah[2], al[2];
#pragma unroll
        for (int m = 0; m < 2; ++m) {
            const int row = mbase + m * 16 + fr;
            ah[m] = *(const short8*)(Ahi + row * 104 + kb * 32 + koff);
            al[m] = *(const short8*)(Alo + row * 104 + kb * 32 + koff);
        }
#pragma unroll
        for (int m = 0; m < 2; ++m)
#pragma unroll
            for (int n = 0; n < 2; ++n) {
                acc[m][n] = __builtin_amdgcn_mfma_f32_16x16x32_bf16(ah[m], bh[n][kb], acc[m][n], 0, 0, 0);
                acc[m][n] = __builtin_amdgcn_mfma_f32_16x16x32_bf16(al[m], bh[n][kb], acc[m][n], 0, 0, 0);
                acc[m][n] = __builtin_amdgcn_mfma_f32_16x16x32_bf16(ah[m], bl[n][kb], acc[m][n], 0, 0, 0);
            }
    }

    // epilogue: bias + ReLU + scatter (C layout: col=lane&15, row=(lane>>4)*4+j)
    const float bv0 = bias[nbase + fr];
    const float bv1 = bias[nbase + 16 + fr];
    const int rb = (lane >> 4) * 4;
#pragma unroll
    for (int m = 0; m < 2; ++m)
#pragma unroll
        for (int j = 0; j < 4; ++j) {
            const int r = mbase + m * 16 + rb + j;
            const int d = ldst[r];
            float v0 = fmaxf(acc[m][0][j] + bv0, 0.f);
            float v1 = fmaxf(acc[m][1][j] + bv1, 0.f);
            unsafeAtomicAdd(&aggr[(size_t)d * 64 + nbase + fr], v0);
            unsafeAtomicAdd(&aggr[(size_t)d * 64 + nbase + 16 + fr], v1);
        }
}

// ---------------------------------------------------------------------------
// h = xin @ Wr + aggr/max(cnt,1); per-block BN partial sums (no atomics).
__global__ __launch_bounds__(256) void k_combine(const float* __restrict__ xin,  // [N,64]
                                                 const float* __restrict__ Wr,   // [64,64]
                                                 const float* __restrict__ aggr, // [N,64]
                                                 const float* __restrict__ cnt,  // [N]
                                                 float* __restrict__ h,          // [N,64]
                                                 float* __restrict__ partial) {  // [NB,128]
    const int lane = threadIdx.x & 63;
    const int wv   = threadIdx.x >> 6;  // wave in block (0..3)
    const int wid  = (blockIdx.x * blockDim.x + threadIdx.x) >> 6;
    const int nw   = (gridDim.x * blockDim.x) >> 6;

    float w[64];
#pragma unroll
    for (int k = 0; k < 64; ++k) w[k] = Wr[k * 64 + lane];

    float rs = 0.f, rq = 0.f;
    for (int n = wid; n < N_NODES; n += nw) {
        const float* __restrict__ xr = xin + (size_t)n * 64;
        const float c = cnt[n];  // uniform
        float acc = aggr[(size_t)n * 64 + lane] / fmaxf(c, 1.0f);
#pragma unroll
        for (int k = 0; k < 64; ++k) acc += xr[k] * w[k];
        h[(size_t)n * 64 + lane] = acc;
        rs += acc;
        rq += acc * acc;
    }
    __shared__ float ssum[4][64];
    __shared__ float ssq[4][64];
    ssum[wv][lane] = rs;
    ssq[wv][lane]  = rq;
    __syncthreads();
    if (threadIdx.x < 64) {
        float s = ssum[0][lane] + ssum[1][lane] + ssum[2][lane] + ssum[3][lane];
        partial[blockIdx.x * 128 + lane] = s;
    } else if (threadIdx.x < 128) {
        int l = threadIdx.x - 64;
        float q = ssq[0][l] + ssq[1][l] + ssq[2][l] + ssq[3][l];
        partial[blockIdx.x * 128 + 64 + l] = q;
    }
}

// ---------------------------------------------------------------------------
// Reduce per-block partials -> per-feature scale/shift. 1 block, 128 threads.
__global__ void k_bnfin(const float* __restrict__ partial, const float* __restrict__ g,
                        const float* __restrict__ be, float* __restrict__ ss) {
    __shared__ float tot[128];
    int t = threadIdx.x;
    float s = 0.f;
    for (int b = 0; b < NB_COMBINE; ++b) s += partial[b * 128 + t];
    tot[t] = s;
    __syncthreads();
    if (t < 64) {
        float mu  = tot[t] * (1.0f / (float)N_NODES);
        float var = tot[64 + t] * (1.0f / (float)N_NODES) - mu * mu;
        float sc  = g[t] * rsqrtf(var + EPS);
        ss[t]      = sc;
        ss[64 + t] = be[t] - mu * sc;
    }
}

// ---------------------------------------------------------------------------
// hn = relu(h * scale + shift), vectorized float4.
__global__ __launch_bounds__(256) void k_bnapply(const float* __restrict__ h,
                                                 const float* __restrict__ ss,
                                                 float* __restrict__ hn) {
    int tid = blockIdx.x * blockDim.x + threadIdx.x;
    int stride = gridDim.x * blockDim.x;
    const int total = N_NODES * 64 / 4;
    for (int i = tid; i < total; i += stride) {
        float4 v = ((const float4*)h)[i];
        int f = (i & 15) * 4;  // (i*4) % 64
        float4 r;
        r.x = fmaxf(v.x * ss[f + 0] + ss[64 + f + 0], 0.f);
        r.y = fmaxf(v.y * ss[f + 1] + ss[64 + f + 1], 0.f);
        r.z = fmaxf(v.z * ss[f + 2] + ss[64 + f + 2], 0.f);
        r.w = fmaxf(v.w * ss[f + 3] + ss[64 + f + 3], 0.f);
        ((float4*)hn)[i] = r;
    }
}

// ---------------------------------------------------------------------------
// Per-graph sums of hn. batch is sorted: each wave owns a contiguous node run,
// accumulates in registers, flushes one atomic per graph transition.
__global__ __launch_bounds__(256) void k_pool(const float* __restrict__ hn,
                                              const int* __restrict__ batch,
                                              float* __restrict__ gsum) {
    const int lane = threadIdx.x & 63;
    const int wid  = (blockIdx.x * blockDim.x + threadIdx.x) >> 6;
    const int nw   = (gridDim.x * blockDim.x) >> 6;
    const int chunk = (N_NODES + nw - 1) / nw;
    const int n0 = wid * chunk;
    const int n1 = min(n0 + chunk, N_NODES);
    int curg = -1;
    float acc = 0.f;
    for (int n = n0; n < n1; ++n) {
        int g = __builtin_amdgcn_readfirstlane(batch[n]);
        if (g != curg) {
            if (curg >= 0) unsafeAtomicAdd(&gsum[curg * 64 + lane], acc);
            curg = g;
            acc = 0.f;
        }
        acc += hn[(size_t)n * 64 + lane];
    }
    if (curg >= 0) unsafeAtomicAdd(&gsum[curg * 64 + lane], acc);
}

// ---------------------------------------------------------------------------
// out[g] = dot(gsum[g]/max(gcnt,1), Wro) + bro
__global__ void k_final(const float* __restrict__ gsum, const float* __restrict__ gcnt,
                        const float* __restrict__ Wro, const float* __restrict__ bro,
                        float* __restrict__ out) {
    int g = blockIdx.x;
    int lane = threadIdx.x;  // 64 threads
    float v = gsum[g * 64 + lane] / fmaxf(gcnt[g], 1.0f) * Wro[lane];
#pragma unroll
    for (int off = 32; off > 0; off >>= 1) v += __shfl_down(v, off, 64);
    if (lane == 0) out[g] = v + bro[0];
}

// ---------------------------------------------------------------------------
extern "C" void kernel_launch(void* const* d_in, const int* in_sizes, int n_in,
                              void* d_out, int out_size, void* d_ws, size_t ws_size,
                              hipStream_t stream) {
    (void)in_sizes; (void)n_in; (void)out_size; (void)ws_size;
    const float* x    = (const float*)d_in[0];
    const int*   ei   = (const int*)d_in[1];   // [2, E]
    const float* ea   = (const float*)d_in[2];
    const int*   batch= (const int*)d_in[3];
    const float* Wn1  = (const float*)d_in[4];
    const float* bn1  = (const float*)d_in[5];
    const float* Wr1  = (const float*)d_in[6];
    const float* g1   = (const float*)d_in[7];
    const float* be1  = (const float*)d_in[8];
    const float* Wn2  = (const float*)d_in[9];
    const float* bn2  = (const float*)d_in[10];
    const float* Wr2  = (const float*)d_in[11];
    const float* g2   = (const float*)d_in[12];
    const float* be2  = (const float*)d_in[13];
    const float* Wro  = (const float*)d_in[14];
    const float* bro  = (const float*)d_in[15];
    const int* src = ei;
    const int* dst = ei + N_EDGES;

    float* ws = (float*)d_ws;
    // zeroed region: [cnt | gsum | aggr]
    float* cnt    = ws;                         // 50048 (padded)
    float* gsum   = cnt + 50048;                // 3200
    float* aggr   = gsum + 3200;                // N*64  <- end of zeroed region
    // non-zeroed:
    float* h      = aggr + (size_t)N_NODES * 64;
    float* hn     = h + (size_t)N_NODES * 64;
    float* gcnt   = hn + (size_t)N_NODES * 64;  // 64
    float* part1  = gcnt + 64;                  // NB_COMBINE*128
    float* part2  = part1 + NB_COMBINE * 128;   // NB_COMBINE*128
    float* ss1    = part2 + NB_COMBINE * 128;   // 128
    float* ss2    = ss1 + 128;                  // 128
    unsigned short* wb = (unsigned short*)(ss2 + 128);  // bf16 weight buffers
    unsigned short* Wh1 = wb;                   // 64*104 each
    unsigned short* Wl1 = wb + 6656;
    unsigned short* Wh2 = wb + 13312;
    unsigned short* Wl2 = wb + 19968;

    size_t zero_floats = (size_t)(50048 + 3200) + (size_t)N_NODES * 64;
    hipMemsetAsync(d_ws, 0, zero_floats * sizeof(float), stream);

    k_count<<<512, 256, 0, stream>>>(dst, cnt);
    k_gcnt<<<1, 64, 0, stream>>>(batch, gcnt);
    k_prepW<<<24, 256, 0, stream>>>(Wn1, Wh1, Wl1);
    k_prepW<<<24, 256, 0, stream>>>(Wn2, Wh2, Wl2);

    // ---- layer 1 ----
    k_edge<<<N_EDGES / 64, 256, 0, stream>>>(x, ea, src, dst, Wh1, Wl1, bn1, aggr);
    k_combine<<<NB_COMBINE, 256, 0, stream>>>(x, Wr1, aggr, cnt, h, part1);
    k_bnfin<<<1, 128, 0, stream>>>(part1, g1, be1, ss1);
    k_bnapply<<<2048, 256, 0, stream>>>(h, ss1, hn);

    // ---- layer 2 ----
    hipMemsetAsync(aggr, 0, (size_t)N_NODES * 64 * sizeof(float), stream);
    k_edge<<<N_EDGES / 64, 256, 0, stream>>>(hn, ea, src, dst, Wh2, Wl2, bn2, aggr);
    k_combine<<<NB_COMBINE, 256, 0, stream>>>(hn, Wr2, aggr, cnt, h, part2);
    k_bnfin<<<1, 128, 0, stream>>>(part2, g2, be2, ss2);
    k_bnapply<<<2048, 256, 0, stream>>>(h, ss2, hn);

    // ---- readout ----
    k_pool<<<256, 256, 0, stream>>>(hn, batch, gsum);
    k_final<<<NUM_GRAPHS, 64, 0, stream>>>(gsum, gcnt, Wro, bro, (float*)d_out);
}

// Round 4
// 472.161 us; speedup vs baseline: 2.2633x; 1.2305x over previous
//
#include <hip/hip_runtime.h>

#define N_NODES   50000
#define N_EDGES   800000
#define HID       64
#define NUM_GRAPHS 50
#define EPS       1e-5f
#define NB_COMBINE 256
#define NHPAD     50176          // 98 * 512, padded histogram/scan size
#define SCAN_B    98

typedef __attribute__((ext_vector_type(8))) short short8;
typedef __attribute__((ext_vector_type(4))) float f32x4;

__device__ __forceinline__ unsigned short bfbits(float x) {
    __bf16 h = (__bf16)x;
    return __builtin_bit_cast(unsigned short, h);
}
__device__ __forceinline__ float bffloat(unsigned short b) {
    return __builtin_bit_cast(float, (unsigned int)b << 16);
}

// ---------------------------------------------------------------------------
// Int histogram of dst (degree count). Random-address atomics, shallow chains.
__global__ __launch_bounds__(256) void k_hist(const int* __restrict__ dst,
                                              int* __restrict__ ihist) {
    int tid = blockIdx.x * blockDim.x + threadIdx.x;
    int stride = gridDim.x * blockDim.x;
    for (int e = tid; e < N_EDGES; e += stride) atomicAdd(&ihist[dst[e]], 1);
}

// Exclusive scan, pass 1: per-block (512 elems) local scan + block sums.
__global__ __launch_bounds__(512) void k_scan1(const int* __restrict__ ihist,
                                               int* __restrict__ off,
                                               int* __restrict__ bsum) {
    __shared__ int s[512];
    const int t = threadIdx.x, i = blockIdx.x * 512 + t;
    const int v = ihist[i];
    s[t] = v;
    __syncthreads();
    for (int o = 1; o < 512; o <<= 1) {
        int u = (t >= o) ? s[t - o] : 0;
        __syncthreads();
        s[t] += u;
        __syncthreads();
    }
    off[i] = s[t] - v;
    if (t == 511) bsum[blockIdx.x] = s[t];
}

// pass 2: serial exclusive scan of the 98 block sums.
__global__ void k_scan2(const int* __restrict__ bsum, int* __restrict__ bscan) {
    if (threadIdx.x == 0) {
        int acc = 0;
        for (int b = 0; b < SCAN_B; ++b) { bscan[b] = acc; acc += bsum[b]; }
    }
}

// pass 3: add block offsets; duplicate into mutable cursor for the scatter.
__global__ __launch_bounds__(512) void k_scan3(int* __restrict__ off,
                                               const int* __restrict__ bscan,
                                               int* __restrict__ off_cur) {
    const int i = blockIdx.x * 512 + threadIdx.x;
    const int v = off[i] + bscan[i >> 9];
    off[i] = v;
    off_cur[i] = v;
}

// Counting-sort scatter: edge arrays reordered by dst.
__global__ __launch_bounds__(256) void k_scatter(const int* __restrict__ src,
                                                 const int* __restrict__ dst,
                                                 int* __restrict__ off_cur,
                                                 int* __restrict__ ssrc,
                                                 int* __restrict__ sdsts,
                                                 int* __restrict__ seid) {
    int tid = blockIdx.x * blockDim.x + threadIdx.x;
    int stride = gridDim.x * blockDim.x;
    for (int e = tid; e < N_EDGES; e += stride) {
        const int d = dst[e];
        const int p = atomicAdd(&off_cur[d], 1);
        ssrc[p] = src[e];
        sdsts[p] = d;
        seid[p] = e;
    }
}

// ---------------------------------------------------------------------------
// Per-graph node counts via binary search on the sorted batch array.
__global__ void k_gcnt(const int* __restrict__ batch, float* __restrict__ gcnt) {
    int g = threadIdx.x;
    if (g >= NUM_GRAPHS) return;
    auto lb = [&](int val) {
        int lo = 0, hi = N_NODES;
        while (lo < hi) { int mid = (lo + hi) >> 1; if (batch[mid] < val) lo = mid + 1; else hi = mid; }
        return lo;
    };
    gcnt[g] = (float)(lb(g + 1) - lb(g));
}

// ---------------------------------------------------------------------------
// Weight prep: W[96][64] fp32 -> Wt hi/lo [64][104] bf16 (transposed, padded).
__global__ void k_prepW(const float* __restrict__ W, unsigned short* __restrict__ Whi,
                        unsigned short* __restrict__ Wlo) {
    int t = blockIdx.x * blockDim.x + threadIdx.x;
    if (t >= 96 * 64) return;
    int k = t >> 6, n = t & 63;
    float x = W[t];
    unsigned short hb = bfbits(x);
    float lof = x - bffloat(hb);
    Whi[n * 104 + k] = hb;
    Wlo[n * 104 + k] = bfbits(lof);
}

// ---------------------------------------------------------------------------
// Edge message via MFMA over 64 dst-sorted edges per block; epilogue does an
// LDS segment-reduce over equal-dst runs, then one coalesced atomic per run.
__global__ __launch_bounds__(256) void k_edge(const float* __restrict__ xin,   // [N,64]
                                              const float* __restrict__ ea,    // [E,32]
                                              const int*   __restrict__ ssrc,  // sorted src
                                              const int*   __restrict__ sdsts, // sorted dst
                                              const int*   __restrict__ seid,  // orig edge id
                                              const unsigned short* __restrict__ Whi, // [64][104]
                                              const unsigned short* __restrict__ Wlo,
                                              const float* __restrict__ bias,  // [64]
                                              float* __restrict__ aggr) {      // [N,64]
    __shared__ __align__(16) char smem[64 * 104 * 2 * sizeof(unsigned short)];
    unsigned short* Ahi = (unsigned short*)smem;
    unsigned short* Alo = Ahi + 64 * 104;
    float* msg = (float*)smem;           // aliases A-staging; valid after barrier
    __shared__ int lsrc[64];
    __shared__ int ldst[64];
    __shared__ int leid[64];

    const int tid  = threadIdx.x;
    const int lane = tid & 63;
    const int w    = tid >> 6;        // wave 0..3
    const int e0   = blockIdx.x * 64;

    const int fr    = lane & 15;
    const int koff  = (lane >> 4) * 8;
    const int nbase = (w & 1) * 32;
    const int mbase = (w >> 1) * 32;

    // B fragments resident: 2 N-tiles x 3 K-blocks x {hi,lo}
    short8 bh[2][3], bl[2][3];
#pragma unroll
    for (int n = 0; n < 2; ++n)
#pragma unroll
        for (int kb = 0; kb < 3; ++kb) {
            const int row = nbase + n * 16 + fr;
            bh[n][kb] = *(const short8*)(Whi + row * 104 + kb * 32 + koff);
            bl[n][kb] = *(const short8*)(Wlo + row * 104 + kb * 32 + koff);
        }

    if (tid < 64) { lsrc[tid] = ssrc[e0 + tid]; ldst[tid] = sdsts[e0 + tid]; leid[tid] = seid[e0 + tid]; }
    __syncthreads();

    // gather x rows -> cols [0,64): 2 rows per wave-iter (float2 per lane)
    {
        const int jj = lane & 31;
        const int half = lane >> 5;
#pragma unroll
        for (int it = 0; it < 8; ++it) {
            const int r = w * 16 + it * 2 + half;
            const int s = lsrc[r];
            float2 v = *((const float2*)(xin + (size_t)s * 64) + jj);
            unsigned short h0 = bfbits(v.x), h1 = bfbits(v.y);
            unsigned short l0 = bfbits(v.x - bffloat(h0));
            unsigned short l1 = bfbits(v.y - bffloat(h1));
            ((unsigned int*)Ahi)[r * 52 + jj] = ((unsigned int)h1 << 16) | h0;
            ((unsigned int*)Alo)[r * 52 + jj] = ((unsigned int)l1 << 16) | l0;
        }
    }
    // gather ea (permuted rows) -> cols [64,96)
#pragma unroll
    for (int it = 0; it < 4; ++it) {
        const int f = tid + it * 256;
        const int e = f >> 4, q = f & 15;
        const int ee = leid[e];
        float2 v = *((const float2*)(ea + (size_t)ee * 32) + q);
        unsigned short h0 = bfbits(v.x), h1 = bfbits(v.y);
        unsigned short l0 = bfbits(v.x - bffloat(h0));
        unsigned short l1 = bfbits(v.y - bffloat(h1));
        ((unsigned int*)Ahi)[e * 52 + 32 + q] = ((unsigned int)h1 << 16) | h0;
        ((unsigned int*)Alo)[e * 52 + 32 + q] = ((unsigned int)l1 << 16) | l0;
    }
    __syncthreads();

    f32x4 acc[2][2] = {};
#pragma unroll
    for (int kb = 0; kb < 3; ++kb) {
        short8 ah[2], al[2];
#pragma unroll
        for (int m = 0; m < 2; ++m) {
            const int row = mbase + m * 16 + fr;
            ah[m] = *(const short8*)(Ahi + row * 104 + kb * 32 + koff);
            al[m] = *(const short8*)(Alo + row * 104 + kb * 32 + koff);
        }
#pragma unroll
        for (int m = 0; m < 2; ++m)
#pragma unroll
            for (int n = 0; n < 2; ++n) {
                acc[m][n] = __builtin_amdgcn_mfma_f32_16x16x32_bf16(ah[m], bh[n][kb], acc[m][n], 0, 0, 0);
                acc[m][n] = __builtin_amdgcn_mfma_f32_16x16x32_bf16(al[m], bh[n][kb], acc[m][n], 0, 0, 0);
                acc[m][n] = __builtin_amdgcn_mfma_f32_16x16x32_bf16(ah[m], bl[n][kb], acc[m][n], 0, 0, 0);
            }
    }
    __syncthreads();  // all A reads done; smem becomes msg[64][68]

    // bias + ReLU, store per-edge messages (C layout: col=lane&15, row=(lane>>4)*4+j)
    const float bv0 = bias[nbase + fr];
    const float bv1 = bias[nbase + 16 + fr];
    const int rb = (lane >> 4) * 4;
#pragma unroll
    for (int m = 0; m < 2; ++m)
#pragma unroll
        for (int j = 0; j < 4; ++j) {
            const int r = mbase + m * 16 + rb + j;
            msg[r * 68 + nbase + fr]      = fmaxf(acc[m][0][j] + bv0, 0.f);
            msg[r * 68 + nbase + 16 + fr] = fmaxf(acc[m][1][j] + bv1, 0.f);
        }
    __syncthreads();

    // strip segment-reduce: wave w owns rows [16w,16w+16), lane owns feature f.
    {
        const int f = lane;
        const int r0 = w * 16;
        int cur = ldst[r0];
        float a2 = 0.f;
        for (int r = r0; r < r0 + 16; ++r) {
            const int d = ldst[r];  // wave-uniform broadcast
            if (d != cur) {
                unsafeAtomicAdd(&aggr[(size_t)cur * 64 + f], a2);
                a2 = 0.f;
                cur = d;
            }
            a2 += msg[r * 68 + f];
        }
        unsafeAtomicAdd(&aggr[(size_t)cur * 64 + f], a2);
    }
}

// ---------------------------------------------------------------------------
// h = xin @ Wr + aggr/max(deg,1); per-block BN partial sums (no atomics).
__global__ __launch_bounds__(256) void k_combine(const float* __restrict__ xin,  // [N,64]
                                                 const float* __restrict__ Wr,   // [64,64]
                                                 const float* __restrict__ aggr, // [N,64]
                                                 const int*   __restrict__ ihist,// [N]
                                                 float* __restrict__ h,          // [N,64]
                                                 float* __restrict__ partial) {  // [NB,128]
    const int lane = threadIdx.x & 63;
    const int wv   = threadIdx.x >> 6;
    const int wid  = (blockIdx.x * blockDim.x + threadIdx.x) >> 6;
    const int nw   = (gridDim.x * blockDim.x) >> 6;

    float w[64];
#pragma unroll
    for (int k = 0; k < 64; ++k) w[k] = Wr[k * 64 + lane];

    float rs = 0.f, rq = 0.f;
    for (int n = wid; n < N_NODES; n += nw) {
        const float* __restrict__ xr = xin + (size_t)n * 64;
        const float c = fmaxf((float)ihist[n], 1.0f);  // uniform
        float acc = aggr[(size_t)n * 64 + lane] / c;
#pragma unroll
        for (int k = 0; k < 64; ++k) acc += xr[k] * w[k];
        h[(size_t)n * 64 + lane] = acc;
        rs += acc;
        rq += acc * acc;
    }
    __shared__ float ssum[4][64];
    __shared__ float ssq[4][64];
    ssum[wv][lane] = rs;
    ssq[wv][lane]  = rq;
    __syncthreads();
    if (threadIdx.x < 64) {
        float s = ssum[0][lane] + ssum[1][lane] + ssum[2][lane] + ssum[3][lane];
        partial[blockIdx.x * 128 + lane] = s;
    } else if (threadIdx.x < 128) {
        int l = threadIdx.x - 64;
        float q = ssq[0][l] + ssq[1][l] + ssq[2][l] + ssq[3][l];
        partial[blockIdx.x * 128 + 64 + l] = q;
    }
}

// ---------------------------------------------------------------------------
__global__ void k_bnfin(const float* __restrict__ partial, const float* __restrict__ g,
                        const float* __restrict__ be, float* __restrict__ ss) {
    __shared__ float tot[128];
    int t = threadIdx.x;
    float s = 0.f;
    for (int b = 0; b < NB_COMBINE; ++b) s += partial[b * 128 + t];
    tot[t] = s;
    __syncthreads();
    if (t < 64) {
        float mu  = tot[t] * (1.0f / (float)N_NODES);
        float var = tot[64 + t] * (1.0f / (float)N_NODES) - mu * mu;
        float sc  = g[t] * rsqrtf(var + EPS);
        ss[t]      = sc;
        ss[64 + t] = be[t] - mu * sc;
    }
}

// ---------------------------------------------------------------------------
__global__ __launch_bounds__(256) void k_bnapply(const float* __restrict__ h,
                                                 const float* __restrict__ ss,
                                                 float* __restrict__ hn) {
    int tid = blockIdx.x * blockDim.x + threadIdx.x;
    int stride = gridDim.x * blockDim.x;
    const int total = N_NODES * 64 / 4;
    for (int i = tid; i < total; i += stride) {
        float4 v = ((const float4*)h)[i];
        int f = (i & 15) * 4;
        float4 r;
        r.x = fmaxf(v.x * ss[f + 0] + ss[64 + f + 0], 0.f);
        r.y = fmaxf(v.y * ss[f + 1] + ss[64 + f + 1], 0.f);
        r.z = fmaxf(v.z * ss[f + 2] + ss[64 + f + 2], 0.f);
        r.w = fmaxf(v.w * ss[f + 3] + ss[64 + f + 3], 0.f);
        ((float4*)hn)[i] = r;
    }
}

// ---------------------------------------------------------------------------
__global__ __launch_bounds__(256) void k_pool(const float* __restrict__ hn,
                                              const int* __restrict__ batch,
                                              float* __restrict__ gsum) {
    const int lane = threadIdx.x & 63;
    const int wid  = (blockIdx.x * blockDim.x + threadIdx.x) >> 6;
    const int nw   = (gridDim.x * blockDim.x) >> 6;
    const int chunk = (N_NODES + nw - 1) / nw;
    const int n0 = wid * chunk;
    const int n1 = min(n0 + chunk, N_NODES);
    int curg = -1;
    float acc = 0.f;
    for (int n = n0; n < n1; ++n) {
        int g = __builtin_amdgcn_readfirstlane(batch[n]);
        if (g != curg) {
            if (curg >= 0) unsafeAtomicAdd(&gsum[curg * 64 + lane], acc);
            curg = g;
            acc = 0.f;
        }
        acc += hn[(size_t)n * 64 + lane];
    }
    if (curg >= 0) unsafeAtomicAdd(&gsum[curg * 64 + lane], acc);
}

// ---------------------------------------------------------------------------
__global__ void k_final(const float* __restrict__ gsum, const float* __restrict__ gcnt,
                        const float* __restrict__ Wro, const float* __restrict__ bro,
                        float* __restrict__ out) {
    int g = blockIdx.x;
    int lane = threadIdx.x;
    float v = gsum[g * 64 + lane] / fmaxf(gcnt[g], 1.0f) * Wro[lane];
#pragma unroll
    for (int off = 32; off > 0; off >>= 1) v += __shfl_down(v, off, 64);
    if (lane == 0) out[g] = v + bro[0];
}

// ---------------------------------------------------------------------------
extern "C" void kernel_launch(void* const* d_in, const int* in_sizes, int n_in,
                              void* d_out, int out_size, void* d_ws, size_t ws_size,
                              hipStream_t stream) {
    (void)in_sizes; (void)n_in; (void)out_size; (void)ws_size;
    const float* x    = (const float*)d_in[0];
    const int*   ei   = (const int*)d_in[1];   // [2, E]
    const float* ea   = (const float*)d_in[2];
    const int*   batch= (const int*)d_in[3];
    const float* Wn1  = (const float*)d_in[4];
    const float* bn1  = (const float*)d_in[5];
    const float* Wr1  = (const float*)d_in[6];
    const float* g1   = (const float*)d_in[7];
    const float* be1  = (const float*)d_in[8];
    const float* Wn2  = (const float*)d_in[9];
    const float* bn2  = (const float*)d_in[10];
    const float* Wr2  = (const float*)d_in[11];
    const float* g2   = (const float*)d_in[12];
    const float* be2  = (const float*)d_in[13];
    const float* Wro  = (const float*)d_in[14];
    const float* bro  = (const float*)d_in[15];
    const int* src = ei;
    const int* dst = ei + N_EDGES;

    float* ws = (float*)d_ws;
    // ---- zeroed region: [gsum | aggr | ihist] ----
    float* gsum   = ws;                               // 3200
    float* aggr   = gsum + 3200;                      // N*64
    int*   ihist  = (int*)(aggr + (size_t)N_NODES * 64); // NHPAD
    const size_t zero_floats = 3200 + (size_t)N_NODES * 64 + NHPAD;
    // ---- non-zeroed ----
    float* h      = (float*)(ihist + NHPAD);
    float* hn     = h + (size_t)N_NODES * 64;
    float* gcnt   = hn + (size_t)N_NODES * 64;        // 64
    float* part1  = gcnt + 64;                        // NB*128
    float* part2  = part1 + NB_COMBINE * 128;
    float* ss1    = part2 + NB_COMBINE * 128;         // 128
    float* ss2    = ss1 + 128;                        // 128
    unsigned short* wb = (unsigned short*)(ss2 + 128);
    unsigned short* Wh1 = wb;                         // 64*104 each
    unsigned short* Wl1 = wb + 6656;
    unsigned short* Wh2 = wb + 13312;
    unsigned short* Wl2 = wb + 19968;
    int* off     = (int*)(wb + 26624);                // NHPAD
    int* off_cur = off + NHPAD;                       // NHPAD
    int* bsum    = off_cur + NHPAD;                   // 128
    int* bscan   = bsum + 128;                        // 128
    int* ssrc    = bscan + 128;                       // E
    int* sdsts   = ssrc + N_EDGES;                    // E
    int* seid    = sdsts + N_EDGES;                   // E

    hipMemsetAsync(d_ws, 0, zero_floats * sizeof(float), stream);

    // ---- edge sort by dst (shared by both layers) ----
    k_hist<<<512, 256, 0, stream>>>(dst, ihist);
    k_scan1<<<SCAN_B, 512, 0, stream>>>(ihist, off, bsum);
    k_scan2<<<1, 64, 0, stream>>>(bsum, bscan);
    k_scan3<<<SCAN_B, 512, 0, stream>>>(off, bscan, off_cur);
    k_scatter<<<512, 256, 0, stream>>>(src, dst, off_cur, ssrc, sdsts, seid);

    k_gcnt<<<1, 64, 0, stream>>>(batch, gcnt);
    k_prepW<<<24, 256, 0, stream>>>(Wn1, Wh1, Wl1);
    k_prepW<<<24, 256, 0, stream>>>(Wn2, Wh2, Wl2);

    // ---- layer 1 ----
    k_edge<<<N_EDGES / 64, 256, 0, stream>>>(x, ea, ssrc, sdsts, seid, Wh1, Wl1, bn1, aggr);
    k_combine<<<NB_COMBINE, 256, 0, stream>>>(x, Wr1, aggr, ihist, h, part1);
    k_bnfin<<<1, 128, 0, stream>>>(part1, g1, be1, ss1);
    k_bnapply<<<2048, 256, 0, stream>>>(h, ss1, hn);

    // ---- layer 2 ----
    hipMemsetAsync(aggr, 0, (size_t)N_NODES * 64 * sizeof(float), stream);
    k_edge<<<N_EDGES / 64, 256, 0, stream>>>(hn, ea, ssrc, sdsts, seid, Wh2, Wl2, bn2, aggr);
    k_combine<<<NB_COMBINE, 256, 0, stream>>>(hn, Wr2, aggr, ihist, h, part2);
    k_bnfin<<<1, 128, 0, stream>>>(part2, g2, be2, ss2);
    k_bnapply<<<2048, 256, 0, stream>>>(h, ss2, hn);

    // ---- readout ----
    k_pool<<<256, 256, 0, stream>>>(hn, batch, gsum);
    k_final<<<NUM_GRAPHS, 64, 0, stream>>>(gsum, gcnt, Wro, bro, (float*)d_out);
}